// Round 11
// baseline (225.561 us; speedup 1.0000x reference)
//
#include <hip/hip_runtime.h>
#include <hip/hip_bf16.h>
#include <stdint.h>

typedef __bf16 bf16;
typedef __bf16 bf16x8 __attribute__((ext_vector_type(8)));
typedef __bf16 bf16x4 __attribute__((ext_vector_type(4)));
typedef short  s16x4  __attribute__((ext_vector_type(4)));
typedef short  s16x8  __attribute__((ext_vector_type(8)));
typedef float  f32x4  __attribute__((ext_vector_type(4)));

#define N_B 4
#define N_T 2048
#define N_D 768
#define N_H 12
#define N_DH 64
#define M_TOT (N_B * N_T)   // 8192

// async global->LDS, 16 bytes per lane. LDS dest must be base + lane*16.
__device__ __forceinline__ void async_copy16(const bf16* g, bf16* l) {
    __builtin_amdgcn_global_load_lds(
        (const __attribute__((address_space(1))) unsigned int*)g,
        (__attribute__((address_space(3))) unsigned int*)l,
        16, 0, 0);
}

// fused fp32 -> bf16 convert for three arrays (each size % 1024 == 0, so
// every 256-thread block stays within one segment). Packed bf16x4 store.
__launch_bounds__(256)
__global__ void f2bf3(const float* __restrict__ a, bf16* __restrict__ oa, int na,
                      const float* __restrict__ b, bf16* __restrict__ ob, int nb,
                      const float* __restrict__ c, bf16* __restrict__ oc) {
    int i = (blockIdx.x * 256 + threadIdx.x) * 4;
    const float* src; bf16* dst;
    if (i < na)            { src = a; dst = oa; }
    else if (i < na + nb)  { src = b; dst = ob; i -= na; }
    else                   { src = c; dst = oc; i -= na + nb; }
    const float4 v = *(const float4*)(src + i);
    bf16x4 o;
    o[0] = (bf16)v.x; o[1] = (bf16)v.y; o[2] = (bf16)v.z; o[3] = (bf16)v.w;
    *(bf16x4*)(dst + i) = o;
}

// ---------------------------------------------------------------------------
// GEMM core: C[m,n] = sum_k A[m,k] * Bt[n,k]  (both K-contiguous, bf16)
// Inner schedule frozen (R6): BK=64, [row][64] LDS + both-sides XOR swizzle
// (0 conflicts), double-buffered, 1 barrier per k-step, prefetch post-barrier.
// R11: WORK-PER-BARRIER dial — rest has been invariant (133-141us) to
// latency hiding (R4), conflicts (R6, +8), and L2 swizzle (R10). m233's
// 2-phase decomposition: stage+barrier chain is the overhead, amortized
// only by MFMA-per-barrier. qkv TN=192 (48 MFMA/wave/k-step, ratio 2.4,
// LDS 80KB = 2 blocks/CU at exactly 160KB); proj TN=96 (grid 512 = exactly
// 2 blocks/CU dispatched AND resident, no tail).
// ---------------------------------------------------------------------------
#define GEMM_STAGE(P, K0)                                                      \
    _Pragma("unroll")                                                          \
    for (int jj = 0; jj < 4; jj++)                                             \
        async_copy16(Ab + (size_t)jj * 32 * KD + (K0), &lsA[P][(jj * 256 + t) * 8]); \
    _Pragma("unroll")                                                          \
    for (int jj = 0; jj < TN / 32; jj++)                                       \
        async_copy16(Bb + (size_t)jj * 32 * KD + (K0), &lsB[P][(jj * 256 + t) * 8]);

#define GEMM_CORE(A_PTR, B_PTR, KDIM, TN_, BX, BY)                             \
    constexpr int KD = (KDIM);                                                 \
    constexpr int TN = (TN_);                                                  \
    constexpr int JJ = TN / 32;                                                \
    constexpr int NT = KD / 64;                                                \
    __shared__ bf16 lsA[2][128 * 64];                                          \
    __shared__ bf16 lsB[2][TN * 64];                                           \
    const int m0 = (BX) * 128;                                                 \
    const int n0 = (BY) * TN;                                                  \
    const int t  = threadIdx.x;                                                \
    const int w  = t >> 6, l = t & 63;                                         \
    const int wm = w & 1, wn = w >> 1;                                         \
    const int lr = l & 15, lq = l >> 4;                                        \
    f32x4 acc[4][JJ] = {};                                                     \
    const int cs = (t & 7) ^ ((t >> 3) & 7);                                   \
    const bf16* Ab = (A_PTR) + (size_t)(m0 + (t >> 3)) * KD + cs * 8;          \
    const bf16* Bb = (B_PTR) + (size_t)(n0 + (t >> 3)) * KD + cs * 8;          \
    GEMM_STAGE(0, 0)                                                           \
    for (int t0 = 0; t0 < NT; t0++) {                                          \
        const int p = t0 & 1;                                                  \
        __syncthreads();                                                       \
        if (t0 + 1 < NT) { GEMM_STAGE(p ^ 1, (t0 + 1) * 64) }                  \
        _Pragma("unroll")                                                      \
        for (int ks = 0; ks < 2; ks++) {                                       \
            bf16x8 af[4], bfr[JJ];                                             \
            _Pragma("unroll")                                                  \
            for (int i = 0; i < 4; i++)                                        \
                af[i] = *(const bf16x8*)(&lsA[p][(wm * 64 + i * 16 + lr) * 64  \
                                         + (((ks * 4 + lq) ^ (lr & 7)) * 8)]); \
            _Pragma("unroll")                                                  \
            for (int j = 0; j < JJ; j++)                                       \
                bfr[j] = *(const bf16x8*)(&lsB[p][(wn * (TN / 2) + j * 16 + lr) * 64 \
                                          + (((ks * 4 + lq) ^ (lr & 7)) * 8)]); \
            _Pragma("unroll")                                                  \
            for (int i = 0; i < 4; i++)                                        \
                _Pragma("unroll")                                              \
                for (int j = 0; j < JJ; j++)                                   \
                    acc[i][j] = __builtin_amdgcn_mfma_f32_16x16x32_bf16(       \
                        af[i], bfr[j], acc[i][j], 0, 0, 0);                    \
        }                                                                      \
    }

// QKV projection: Xb * Wb^T + b_qkv.  TN=192 (768 = 4*192, so a tile never
// straddles the Q/K/V boundary). Grid 64x12 = 768 blocks, 1D, XCD-contiguous
// + by-sextet panel grouping.
// Q: [B,H,T,64] pre-scaled by 0.125*log2(e) (softmax in base-2);
// K: [B,H,T,64]; V: transposed [B,H,64,T] with keys PERMUTED inside each
// 64-token tile so PV can run on 16x16x32 MFMA:
//   physical key p (ki=p>>4, lq=(p>>2)&3, r=p&3) lands at logical slot
//   s = 32*(ki&1) + 8*lq + 4*(ki>>1) + r.
__launch_bounds__(256)
__global__ void gemm_qkv(const bf16* __restrict__ X, const bf16* __restrict__ W,
                         const float* __restrict__ bias,
                         bf16* __restrict__ Q, bf16* __restrict__ K,
                         bf16* __restrict__ Vt) {
    const int id    = blockIdx.x;
    const int lid   = (id & 7) * 96 + (id >> 3);      // 768 = 8 * 96
    const int chunk = lid / 384;                      // 384 = 64 bx * 6 by
    const int rrr   = lid - chunk * 384;
    const int bxx   = rrr / 6;
    const int byy   = chunk * 6 + (rrr - bxx * 6);
    GEMM_CORE(X, W, 768, 192, bxx, byy)
    // epilogue: C/D layout col=lane&15, row=(lane>>4)*4+reg
    for (int i = 0; i < 4; i++) {
        const int rowb = m0 + wm * 64 + i * 16 + lq * 4;
        const int b_ = rowb >> 11, tt = rowb & 2047;   // 128-tiles never straddle batch
        for (int j = 0; j < JJ; j++) {
            const int col   = n0 + wn * (TN / 2) + j * 16 + lr;
            const int which = col / 768;
            const int rem   = col - which * 768;
            const int h     = rem >> 6, d = rem & 63;
            const float bv  = bias[col];
            if (which == 2) {
                // V^T with x32-friendly key permutation (tt multiple of 4 so
                // kl&3 = 0 at the base; r2 walks 4 consecutive slots)
                const int tile = tt >> 6, kl = tt & 63;
                const int ki = kl >> 4, lqv = (kl >> 2) & 3;
                const int idx = 32 * (ki & 1) + 8 * lqv + 4 * (ki >> 1);
                bf16x4 v4;
                for (int r2 = 0; r2 < 4; r2++) v4[r2] = (bf16)(acc[i][j][r2] + bv);
                *(bf16x4*)(Vt + ((size_t)((b_ * N_H + h) * 64 + d)) * 2048
                           + tile * 64 + idx) = v4;
            } else {
                bf16* dst = (which == 0) ? Q : K;
                const float sc = (which == 0) ? 0.18033688f : 1.0f;  // 1/8 * log2(e)
                for (int r2 = 0; r2 < 4; r2++)
                    dst[(size_t)(((b_ * N_H + h) << 11) + tt + r2) * 64 + d] =
                        (bf16)((acc[i][j][r2] + bv) * sc);
            }
        }
    }
}

// Output projection: Ob[8192x768] * Wpb[768x768]^T + b_proj -> out fp32
// TN=96: grid 64x8 = 512 blocks = EXACTLY 2/CU dispatched and resident
// (56KB LDS x2 = 112KB); no tail imbalance.
__launch_bounds__(256)
__global__ void gemm_proj(const bf16* __restrict__ O, const bf16* __restrict__ W,
                          const float* __restrict__ bias, float* __restrict__ out) {
    const int id    = blockIdx.x;
    const int lid   = (id & 7) * 64 + (id >> 3);      // 512 = 8 * 64
    const int chunk = lid / 256;                      // 256 = 64 bx * 4 by
    const int rrr   = lid - chunk * 256;
    const int bxx   = rrr / 4;
    const int byy   = chunk * 4 + (rrr - bxx * 4);
    GEMM_CORE(O, W, 768, 96, bxx, byy)
    for (int i = 0; i < 4; i++) {
        const int rowb = m0 + wm * 64 + i * 16 + lq * 4;
        for (int j = 0; j < JJ; j++) {
            const int col  = n0 + wn * (TN / 2) + j * 16 + lr;
            const float bv = bias[col];
            for (int r = 0; r < 4; r++)
                out[(size_t)(rowb + r) * 768 + col] = acc[i][j][r] + bv;
        }
    }
}

// ---------------------------------------------------------------------------
// Flash attention, 32-q-per-wave, ALL-x32 MFMA — R8 champion body (86.1us).
// CLOSED as structural: 86-88us across 5 schedules (2-barrier dbuf /
// reorder / counted-vmcnt 3-buf / no-LDS all tested; no-LDS = 186us).
// Pipe accounting: LDS ~42% + MFMA ~32% + VALU ~30% of wall — bound by the
// sum of three pipes at this decomposition.
// 3 LDS buffers, prefetch 2 tiles ahead, barrier = vmcnt(4)+lgkmcnt(0).
// Same algebra: S^T = K Q^T; O^T = V^T P^T; l via ones-MFMA;
// UNSHIFTED base-2 softmax, normalized once at the end.
// ---------------------------------------------------------------------------
__launch_bounds__(256, 3)
__global__ void attn(const bf16* __restrict__ Q, const bf16* __restrict__ K,
                     const bf16* __restrict__ Vt, bf16* __restrict__ O) {
    __shared__ bf16 lsK[3][64 * 64];
    __shared__ bf16 lsV[3][64 * 64];
    const int bid = blockIdx.x;
    const int xcd = bid & 7, slot = bid >> 3;
    const int bh  = xcd + 8 * (slot >> 4);   // 0..47, 6 heads per XCD
    const int qt  = slot & 15;               // 0..15
    const int t = threadIdx.x, w = t >> 6, l = t & 63;
    const int lr = l & 15, lq = l >> 4;
    const bf16* Qh  = Q  + (size_t)bh * N_T * 64;
    const bf16* Kh  = K  + (size_t)bh * N_T * 64;
    const bf16* Vth = Vt + (size_t)bh * 64 * N_T;
    const int q0 = qt * 128 + w * 32;        // this wave's q base (32 rows)

    // Q fragments for 2 q-groups (B-operand, n=q=lr, k=d)
    bf16x8 qf[2][2];
    #pragma unroll
    for (int qg = 0; qg < 2; qg++)
        #pragma unroll
        for (int ks = 0; ks < 2; ks++)
            qf[qg][ks] = *(const bf16x8*)(Qh + (size_t)(q0 + qg * 16 + lr) * 64
                                          + ks * 32 + lq * 8);

    f32x4 oacc[2][4] = {};                   // [qg] O^T[d = dj*16+lq*4+r][q=lr]
    f32x4 lacc[2]    = {};                   // [qg] l(q) via ones-MFMA
    const bf16x8 ones8 = {(bf16)1.f, (bf16)1.f, (bf16)1.f, (bf16)1.f,
                          (bf16)1.f, (bf16)1.f, (bf16)1.f, (bf16)1.f};

    // staging map: thread t covers units u = t, t+256 of each 64x64 tile;
    // row = u>>3, dest chunk u&7, source chunk (u&7)^(row&7) (XOR swizzle,
    // matched by the read side; measured 0 conflicts).
    // prologue: stage tiles 0 and 1 into buffers 0 and 1 (2-deep).
    #pragma unroll
    for (int tile = 0; tile < 2; tile++)
        #pragma unroll
        for (int j = 0; j < 2; j++) {
            const int u   = t + j * 256;     // 0..511
            const int row = u >> 3;          // 0..63
            const int scn = (u & 7) ^ (row & 7);
            async_copy16(Kh  + (size_t)(tile * 64 + row) * 64 + scn * 8,
                         lsK[tile] + u * 8);
            async_copy16(Vth + (size_t)row * 2048 + tile * 64 + scn * 8,
                         lsV[tile] + u * 8);
        }

    int cur = 0;
    for (int kt = 0; kt < 32; kt++) {
        // counted-vmcnt barrier: keep tile kt+1's 4 copies in flight.
        if (kt < 31)
            asm volatile("s_waitcnt vmcnt(4) lgkmcnt(0)\n\ts_barrier" ::: "memory");
        else
            asm volatile("s_waitcnt vmcnt(0) lgkmcnt(0)\n\ts_barrier" ::: "memory");

        if (kt < 30) {     // prefetch tile kt+2 into buffer (cur+2)%3
            int nb = cur + 2; if (nb >= 3) nb -= 3;
            #pragma unroll
            for (int j = 0; j < 2; j++) {
                const int u   = t + j * 256;
                const int row = u >> 3;
                const int scn = (u & 7) ^ (row & 7);
                async_copy16(Kh + (size_t)((kt + 2) * 64 + row) * 64 + scn * 8,
                             lsK[nb] + u * 8);
                async_copy16(Vth + (size_t)row * 2048 + (kt + 2) * 64 + scn * 8,
                             lsV[nb] + u * 8);
            }
        }

        // ---- K fragments: read ONCE, reused across both q-groups ----
        bf16x8 kf[2][4];
        #pragma unroll
        for (int ks = 0; ks < 2; ks++)
            #pragma unroll
            for (int ki = 0; ki < 4; ki++) {
                const int row = ki * 16 + lr;
                kf[ks][ki] = *(const bf16x8*)(lsK[cur] + row * 64
                                              + ((ks * 4 + lq) ^ (lr & 7)) * 8);
            }

        // ---- S^T = K Q^T per q-group; p = exp2(s); pack bf16x8 for x32 ----
        bf16x8 pbf[2][2];                    // [qg][ks] B-operand of x32 PV
        #pragma unroll
        for (int qg = 0; qg < 2; qg++) {
            f32x4 sacc[4] = {};              // S^T[key = ki*16+lq*4+r][q=lr]
            __builtin_amdgcn_s_setprio(1);
            #pragma unroll
            for (int ks = 0; ks < 2; ks++)
                #pragma unroll
                for (int ki = 0; ki < 4; ki++)
                    sacc[ki] = __builtin_amdgcn_mfma_f32_16x16x32_bf16(
                        kf[ks][ki], qf[qg][ks], sacc[ki], 0, 0, 0);
            __builtin_amdgcn_s_setprio(0);
            // logical slot s(p)=32*(ki&1)+8*lq+4*(ki>>1)+r: ks-block ki&1,
            // j = 4*(ki>>1) + r  ->  pbf[ks] = {exp2 sacc[ks], exp2 sacc[ks+2]}
            #pragma unroll
            for (int ks = 0; ks < 2; ks++) {
                bf16x8 pb;
                #pragma unroll
                for (int r = 0; r < 4; r++) {
                    pb[r]     = (bf16)exp2f(sacc[ks][r]);
                    pb[4 + r] = (bf16)exp2f(sacc[ks + 2][r]);
                }
                pbf[qg][ks] = pb;
            }
        }

        // ---- O^T += V^T P^T (x32): V-frags read once, reused per qg ----
        __builtin_amdgcn_s_setprio(1);
        #pragma unroll
        for (int ks = 0; ks < 2; ks++)
            #pragma unroll
            for (int dj = 0; dj < 4; dj++) {
                const int row  = dj * 16 + lr;
                const int unit = (4 * ks + lq) ^ (lr & 7);
                bf16x8 vf = *(const bf16x8*)(lsV[cur] + row * 64 + unit * 8);
                #pragma unroll
                for (int qg = 0; qg < 2; qg++)
                    oacc[qg][dj] = __builtin_amdgcn_mfma_f32_16x16x32_bf16(
                        vf, pbf[qg][ks], oacc[qg][dj], 0, 0, 0);
            }
        // ---- l += 1 . P^T (matrix pipe, x32) ----
        #pragma unroll
        for (int qg = 0; qg < 2; qg++)
            #pragma unroll
            for (int ks = 0; ks < 2; ks++)
                lacc[qg] = __builtin_amdgcn_mfma_f32_16x16x32_bf16(
                    ones8, pbf[qg][ks], lacc[qg], 0, 0, 0);
        __builtin_amdgcn_s_setprio(0);

        cur = cur + 1; if (cur == 3) cur = 0;
    }

    // ---- epilogue: O^T/l -> O [B,T,H*64] bf16, 8B packed stores ----
    const int b = bh / N_H, h = bh - b * N_H;
    #pragma unroll
    for (int qg = 0; qg < 2; qg++) {
        const float inv_l = 1.0f / lacc[qg][0];  // all 4 regs hold l(q=lr)
        const int tok = q0 + qg * 16 + lr;
        bf16* Ob = O + ((size_t)b * N_T + tok) * N_D + h * 64;
        #pragma unroll
        for (int dj = 0; dj < 4; dj++) {
            bf16x4 o4;
            #pragma unroll
            for (int r = 0; r < 4; r++) o4[r] = (bf16)(oacc[qg][dj][r] * inv_l);
            *(bf16x4*)(Ob + dj * 16 + lq * 4) = o4;
        }
    }
}

extern "C" void kernel_launch(void* const* d_in, const int* in_sizes, int n_in,
                              void* d_out, int out_size, void* d_ws, size_t ws_size,
                              hipStream_t stream) {
    const float* x      = (const float*)d_in[0];
    const float* W_qkv  = (const float*)d_in[1];
    const float* b_qkv  = (const float*)d_in[2];
    const float* W_proj = (const float*)d_in[3];
    const float* b_proj = (const float*)d_in[4];
    float* out = (float*)d_out;

    char* ws = (char*)d_ws;
    const size_t n_x  = (size_t)M_TOT * N_D;        // 6291456
    const size_t n_wq = (size_t)3 * N_D * N_D;      // 1769472
    const size_t n_wp = (size_t)N_D * N_D;          // 589824
    const size_t sz_qkv = (size_t)N_B * N_H * N_T * N_DH * sizeof(bf16);  // 12.58 MB

    bf16* xb  = (bf16*)(ws);                 ws += n_x * sizeof(bf16);
    bf16* Wqb = (bf16*)(ws);                 ws += n_wq * sizeof(bf16);
    bf16* Wpb = (bf16*)(ws);                 ws += n_wp * sizeof(bf16);
    bf16* Qb  = (bf16*)(ws);                 ws += sz_qkv;
    bf16* Kb  = (bf16*)(ws);                 ws += sz_qkv;
    bf16* Vtb = (bf16*)(ws);                 ws += sz_qkv;
    bf16* Ob  = (bf16*)(ws);

    dim3 blk(256);
    f2bf3<<<dim3((int)((n_x + n_wq + n_wp) / 1024)), blk, 0, stream>>>(
        x, xb, (int)n_x, W_qkv, Wqb, (int)n_wq, W_proj, Wpb);

    gemm_qkv<<<dim3(768), blk, 0, stream>>>(xb, Wqb, b_qkv, Qb, Kb, Vtb);
    attn<<<dim3(768), dim3(256), 0, stream>>>(Qb, Kb, Vtb, Ob);
    gemm_proj<<<dim3(512), blk, 0, stream>>>(Ob, Wpb, b_proj, out);
}

// Round 12
// 216.549 us; speedup vs baseline: 1.0416x; 1.0416x over previous
//
#include <hip/hip_runtime.h>
#include <hip/hip_bf16.h>
#include <stdint.h>

typedef __bf16 bf16;
typedef __bf16 bf16x8 __attribute__((ext_vector_type(8)));
typedef __bf16 bf16x4 __attribute__((ext_vector_type(4)));
typedef short  s16x4  __attribute__((ext_vector_type(4)));
typedef short  s16x8  __attribute__((ext_vector_type(8)));
typedef float  f32x4  __attribute__((ext_vector_type(4)));

#define N_B 4
#define N_T 2048
#define N_D 768
#define N_H 12
#define N_DH 64
#define M_TOT (N_B * N_T)   // 8192

#define GSTR2(x) #x
#define GSTR(x) GSTR2(x)

// async global->LDS, 16 bytes per lane. LDS dest must be base + lane*16.
__device__ __forceinline__ void async_copy16(const bf16* g, bf16* l) {
    __builtin_amdgcn_global_load_lds(
        (const __attribute__((address_space(1))) unsigned int*)g,
        (__attribute__((address_space(3))) unsigned int*)l,
        16, 0, 0);
}

// fused fp32 -> bf16 convert for three arrays (each size % 1024 == 0, so
// every 256-thread block stays within one segment). Packed bf16x4 store.
__launch_bounds__(256)
__global__ void f2bf3(const float* __restrict__ a, bf16* __restrict__ oa, int na,
                      const float* __restrict__ b, bf16* __restrict__ ob, int nb,
                      const float* __restrict__ c, bf16* __restrict__ oc) {
    int i = (blockIdx.x * 256 + threadIdx.x) * 4;
    const float* src; bf16* dst;
    if (i < na)            { src = a; dst = oa; }
    else if (i < na + nb)  { src = b; dst = ob; i -= na; }
    else                   { src = c; dst = oc; i -= na + nb; }
    const float4 v = *(const float4*)(src + i);
    bf16x4 o;
    o[0] = (bf16)v.x; o[1] = (bf16)v.y; o[2] = (bf16)v.z; o[3] = (bf16)v.w;
    *(bf16x4*)(dst + i) = o;
}

// ---------------------------------------------------------------------------
// GEMM core: C[m,n] = sum_k A[m,k] * Bt[n,k]  (both K-contiguous, bf16)
// Geometry = R6 best (BK=64, [row][64] LDS + both-sides XOR swizzle, 0
// conflicts; TN=128 qkv 2/CU, TN=64 proj 3/CU; 2D grids — R10/R11 variants
// were null-to-negative).
// R12: COUNTED-VMCNT schedule (T4) — the one untested GEMM theory. L2 is
// 4MB PER XCD (not shared): each XCD's working set (all of X, 12.6MB, +W)
// exceeds it, so staging loads are often L3-served (~500cy) — longer than
// the ~400cy MFMA shadow — and __syncthreads' vmcnt(0) drain exposed the
// difference every k-step. New per-k-step structure:
//   ds_read tile t (all frags) -> [lgkmcnt(0); s_barrier]   (no vmcnt drain)
//   stage tile t+2 into the just-read buffer -> MFMA
//   [vmcnt(C); s_barrier]  C = copies/stage (8 qkv, 6 proj):
//     drains tile t+1's copies, keeps t+2's in flight (~1.7 k-steps).
// Race audit: buffer overwritten only after the lgkm-guarded barrier (all
// waves' reads retired); vmcnt is per-wave in-order so vmcnt(C) == "all
// older copies landed"; barrier conditions uniform in t0. Prologue stages
// tiles 0,1 then waits vmcnt(C) (tile 0 landed, tile 1 in flight).
// ---------------------------------------------------------------------------
#define GEMM_STAGE(P, K0)                                                      \
    _Pragma("unroll")                                                          \
    for (int jj = 0; jj < 4; jj++)                                             \
        async_copy16(Ab + (size_t)jj * 32 * KD + (K0), &lsA[P][(jj * 256 + t) * 8]); \
    _Pragma("unroll")                                                          \
    for (int jj = 0; jj < TN / 32; jj++)                                       \
        async_copy16(Bb + (size_t)jj * 32 * KD + (K0), &lsB[P][(jj * 256 + t) * 8]);

#define GEMM_CORE(A_PTR, B_PTR, KDIM, TN_, VMC)                                \
    constexpr int KD = (KDIM);                                                 \
    constexpr int TN = (TN_);                                                  \
    constexpr int JJ = TN / 32;                                                \
    constexpr int NT = KD / 64;                                                \
    __shared__ bf16 lsA[2][128 * 64];                                          \
    __shared__ bf16 lsB[2][TN * 64];                                           \
    const int m0 = blockIdx.x * 128;                                           \
    const int n0 = blockIdx.y * TN;                                            \
    const int t  = threadIdx.x;                                                \
    const int w  = t >> 6, l = t & 63;                                         \
    const int wm = w & 1, wn = w >> 1;                                         \
    const int lr = l & 15, lq = l >> 4;                                        \
    f32x4 acc[4][JJ] = {};                                                     \
    const int cs = (t & 7) ^ ((t >> 3) & 7);                                   \
    const bf16* Ab = (A_PTR) + (size_t)(m0 + (t >> 3)) * KD + cs * 8;          \
    const bf16* Bb = (B_PTR) + (size_t)(n0 + (t >> 3)) * KD + cs * 8;          \
    GEMM_STAGE(0, 0)                                                           \
    GEMM_STAGE(1, 64)                                                          \
    asm volatile("s_waitcnt vmcnt(" GSTR(VMC) ")\n\ts_barrier" ::: "memory");  \
    for (int t0 = 0; t0 < NT; t0++) {                                          \
        const int p = t0 & 1;                                                  \
        bf16x8 af[2][4], bfr[2][JJ];                                           \
        _Pragma("unroll")                                                      \
        for (int ks = 0; ks < 2; ks++) {                                       \
            _Pragma("unroll")                                                  \
            for (int i = 0; i < 4; i++)                                        \
                af[ks][i] = *(const bf16x8*)(&lsA[p][(wm * 64 + i * 16 + lr) * 64 \
                                             + (((ks * 4 + lq) ^ (lr & 7)) * 8)]); \
            _Pragma("unroll")                                                  \
            for (int j = 0; j < JJ; j++)                                       \
                bfr[ks][j] = *(const bf16x8*)(&lsB[p][(wn * (TN / 2) + j * 16 + lr) * 64 \
                                              + (((ks * 4 + lq) ^ (lr & 7)) * 8)]); \
        }                                                                      \
        asm volatile("s_waitcnt lgkmcnt(0)\n\ts_barrier" ::: "memory");        \
        if (t0 + 2 < NT) { GEMM_STAGE(p, (t0 + 2) * 64) }                      \
        _Pragma("unroll")                                                      \
        for (int ks = 0; ks < 2; ks++)                                         \
            _Pragma("unroll")                                                  \
            for (int i = 0; i < 4; i++)                                        \
                _Pragma("unroll")                                              \
                for (int j = 0; j < JJ; j++)                                   \
                    acc[i][j] = __builtin_amdgcn_mfma_f32_16x16x32_bf16(       \
                        af[ks][i], bfr[ks][j], acc[i][j], 0, 0, 0);            \
        if (t0 + 1 < NT) {                                                     \
            if (t0 + 2 < NT)                                                   \
                asm volatile("s_waitcnt vmcnt(" GSTR(VMC) ")\n\ts_barrier" ::: "memory"); \
            else                                                               \
                asm volatile("s_waitcnt vmcnt(0)\n\ts_barrier" ::: "memory");  \
        }                                                                      \
    }

// QKV projection: Xb * Wb^T + b_qkv.  TN=128, grid (64, 18).
// Q: [B,H,T,64] pre-scaled by 0.125*log2(e) (softmax in base-2);
// K: [B,H,T,64]; V: transposed [B,H,64,T] with keys PERMUTED inside each
// 64-token tile so PV can run on 16x16x32 MFMA:
//   physical key p (ki=p>>4, lq=(p>>2)&3, r=p&3) lands at logical slot
//   s = 32*(ki&1) + 8*lq + 4*(ki>>1) + r.
__launch_bounds__(256)
__global__ void gemm_qkv(const bf16* __restrict__ X, const bf16* __restrict__ W,
                         const float* __restrict__ bias,
                         bf16* __restrict__ Q, bf16* __restrict__ K,
                         bf16* __restrict__ Vt) {
    GEMM_CORE(X, W, 768, 128, 8)
    // epilogue: C/D layout col=lane&15, row=(lane>>4)*4+reg
    for (int i = 0; i < 4; i++) {
        const int rowb = m0 + wm * 64 + i * 16 + lq * 4;
        const int b_ = rowb >> 11, tt = rowb & 2047;   // 128-tiles never straddle batch
        for (int j = 0; j < JJ; j++) {
            const int col   = n0 + wn * 64 + j * 16 + lr;
            const int which = col / 768;
            const int rem   = col - which * 768;
            const int h     = rem >> 6, d = rem & 63;
            const float bv  = bias[col];
            if (which == 2) {
                // V^T with x32-friendly key permutation (tt multiple of 4 so
                // kl&3 = 0 at the base; r2 walks 4 consecutive slots)
                const int tile = tt >> 6, kl = tt & 63;
                const int ki = kl >> 4, lqv = (kl >> 2) & 3;
                const int idx = 32 * (ki & 1) + 8 * lqv + 4 * (ki >> 1);
                bf16x4 v4;
                for (int r2 = 0; r2 < 4; r2++) v4[r2] = (bf16)(acc[i][j][r2] + bv);
                *(bf16x4*)(Vt + ((size_t)((b_ * N_H + h) * 64 + d)) * 2048
                           + tile * 64 + idx) = v4;
            } else {
                bf16* dst = (which == 0) ? Q : K;
                const float sc = (which == 0) ? 0.18033688f : 1.0f;  // 1/8 * log2(e)
                for (int r2 = 0; r2 < 4; r2++)
                    dst[(size_t)(((b_ * N_H + h) << 11) + tt + r2) * 64 + d] =
                        (bf16)((acc[i][j][r2] + bv) * sc);
            }
        }
    }
}

// Output projection: Ob[8192x768] * Wpb[768x768]^T + b_proj -> out fp32
// TN=64, grid (64, 12) = 768 blocks = 3/CU (48KB LDS).
__launch_bounds__(256)
__global__ void gemm_proj(const bf16* __restrict__ O, const bf16* __restrict__ W,
                          const float* __restrict__ bias, float* __restrict__ out) {
    GEMM_CORE(O, W, 768, 64, 6)
    for (int i = 0; i < 4; i++) {
        const int rowb = m0 + wm * 64 + i * 16 + lq * 4;
        for (int j = 0; j < JJ; j++) {
            const int col  = n0 + wn * (TN / 2) + j * 16 + lr;
            const float bv = bias[col];
            for (int r = 0; r < 4; r++)
                out[(size_t)(rowb + r) * 768 + col] = acc[i][j][r] + bv;
        }
    }
}

// ---------------------------------------------------------------------------
// Flash attention, 32-q-per-wave, ALL-x32 MFMA — R8 champion body (86.1us).
// CLOSED as structural: 86-88us across 5 schedules (2-barrier dbuf /
// reorder / counted-vmcnt 3-buf / no-LDS all tested; no-LDS = 186us).
// 3 LDS buffers, prefetch 2 tiles ahead, barrier = vmcnt(4)+lgkmcnt(0).
// Same algebra: S^T = K Q^T; O^T = V^T P^T; l via ones-MFMA;
// UNSHIFTED base-2 softmax, normalized once at the end.
// ---------------------------------------------------------------------------
__launch_bounds__(256, 3)
__global__ void attn(const bf16* __restrict__ Q, const bf16* __restrict__ K,
                     const bf16* __restrict__ Vt, bf16* __restrict__ O) {
    __shared__ bf16 lsK[3][64 * 64];
    __shared__ bf16 lsV[3][64 * 64];
    const int bid = blockIdx.x;
    const int xcd = bid & 7, slot = bid >> 3;
    const int bh  = xcd + 8 * (slot >> 4);   // 0..47, 6 heads per XCD
    const int qt  = slot & 15;               // 0..15
    const int t = threadIdx.x, w = t >> 6, l = t & 63;
    const int lr = l & 15, lq = l >> 4;
    const bf16* Qh  = Q  + (size_t)bh * N_T * 64;
    const bf16* Kh  = K  + (size_t)bh * N_T * 64;
    const bf16* Vth = Vt + (size_t)bh * 64 * N_T;
    const int q0 = qt * 128 + w * 32;        // this wave's q base (32 rows)

    // Q fragments for 2 q-groups (B-operand, n=q=lr, k=d)
    bf16x8 qf[2][2];
    #pragma unroll
    for (int qg = 0; qg < 2; qg++)
        #pragma unroll
        for (int ks = 0; ks < 2; ks++)
            qf[qg][ks] = *(const bf16x8*)(Qh + (size_t)(q0 + qg * 16 + lr) * 64
                                          + ks * 32 + lq * 8);

    f32x4 oacc[2][4] = {};                   // [qg] O^T[d = dj*16+lq*4+r][q=lr]
    f32x4 lacc[2]    = {};                   // [qg] l(q) via ones-MFMA
    const bf16x8 ones8 = {(bf16)1.f, (bf16)1.f, (bf16)1.f, (bf16)1.f,
                          (bf16)1.f, (bf16)1.f, (bf16)1.f, (bf16)1.f};

    // staging map: thread t covers units u = t, t+256 of each 64x64 tile;
    // row = u>>3, dest chunk u&7, source chunk (u&7)^(row&7) (XOR swizzle,
    // matched by the read side; measured 0 conflicts).
    // prologue: stage tiles 0 and 1 into buffers 0 and 1 (2-deep).
    #pragma unroll
    for (int tile = 0; tile < 2; tile++)
        #pragma unroll
        for (int j = 0; j < 2; j++) {
            const int u   = t + j * 256;     // 0..511
            const int row = u >> 3;          // 0..63
            const int scn = (u & 7) ^ (row & 7);
            async_copy16(Kh  + (size_t)(tile * 64 + row) * 64 + scn * 8,
                         lsK[tile] + u * 8);
            async_copy16(Vth + (size_t)row * 2048 + tile * 64 + scn * 8,
                         lsV[tile] + u * 8);
        }

    int cur = 0;
    for (int kt = 0; kt < 32; kt++) {
        // counted-vmcnt barrier: keep tile kt+1's 4 copies in flight.
        if (kt < 31)
            asm volatile("s_waitcnt vmcnt(4) lgkmcnt(0)\n\ts_barrier" ::: "memory");
        else
            asm volatile("s_waitcnt vmcnt(0) lgkmcnt(0)\n\ts_barrier" ::: "memory");

        if (kt < 30) {     // prefetch tile kt+2 into buffer (cur+2)%3
            int nb = cur + 2; if (nb >= 3) nb -= 3;
            #pragma unroll
            for (int j = 0; j < 2; j++) {
                const int u   = t + j * 256;
                const int row = u >> 3;
                const int scn = (u & 7) ^ (row & 7);
                async_copy16(Kh + (size_t)((kt + 2) * 64 + row) * 64 + scn * 8,
                             lsK[nb] + u * 8);
                async_copy16(Vth + (size_t)row * 2048 + (kt + 2) * 64 + scn * 8,
                             lsV[nb] + u * 8);
            }
        }

        // ---- K fragments: read ONCE, reused across both q-groups ----
        bf16x8 kf[2][4];
        #pragma unroll
        for (int ks = 0; ks < 2; ks++)
            #pragma unroll
            for (int ki = 0; ki < 4; ki++) {
                const int row = ki * 16 + lr;
                kf[ks][ki] = *(const bf16x8*)(lsK[cur] + row * 64
                                              + ((ks * 4 + lq) ^ (lr & 7)) * 8);
            }

        // ---- S^T = K Q^T per q-group; p = exp2(s); pack bf16x8 for x32 ----
        bf16x8 pbf[2][2];                    // [qg][ks] B-operand of x32 PV
        #pragma unroll
        for (int qg = 0; qg < 2; qg++) {
            f32x4 sacc[4] = {};              // S^T[key = ki*16+lq*4+r][q=lr]
            __builtin_amdgcn_s_setprio(1);
            #pragma unroll
            for (int ks = 0; ks < 2; ks++)
                #pragma unroll
                for (int ki = 0; ki < 4; ki++)
                    sacc[ki] = __builtin_amdgcn_mfma_f32_16x16x32_bf16(
                        kf[ks][ki], qf[qg][ks], sacc[ki], 0, 0, 0);
            __builtin_amdgcn_s_setprio(0);
            // logical slot s(p)=32*(ki&1)+8*lq+4*(ki>>1)+r: ks-block ki&1,
            // j = 4*(ki>>1) + r  ->  pbf[ks] = {exp2 sacc[ks], exp2 sacc[ks+2]}
            #pragma unroll
            for (int ks = 0; ks < 2; ks++) {
                bf16x8 pb;
                #pragma unroll
                for (int r = 0; r < 4; r++) {
                    pb[r]     = (bf16)exp2f(sacc[ks][r]);
                    pb[4 + r] = (bf16)exp2f(sacc[ks + 2][r]);
                }
                pbf[qg][ks] = pb;
            }
        }

        // ---- O^T += V^T P^T (x32): V-frags read once, reused per qg ----
        __builtin_amdgcn_s_setprio(1);
        #pragma unroll
        for (int ks = 0; ks < 2; ks++)
            #pragma unroll
            for (int dj = 0; dj < 4; dj++) {
                const int row  = dj * 16 + lr;
                const int unit = (4 * ks + lq) ^ (lr & 7);
                bf16x8 vf = *(const bf16x8*)(lsV[cur] + row * 64 + unit * 8);
                #pragma unroll
                for (int qg = 0; qg < 2; qg++)
                    oacc[qg][dj] = __builtin_amdgcn_mfma_f32_16x16x32_bf16(
                        vf, pbf[qg][ks], oacc[qg][dj], 0, 0, 0);
            }
        // ---- l += 1 . P^T (matrix pipe, x32) ----
        #pragma unroll
        for (int qg = 0; qg < 2; qg++)
            #pragma unroll
            for (int ks = 0; ks < 2; ks++)
                lacc[qg] = __builtin_amdgcn_mfma_f32_16x16x32_bf16(
                    ones8, pbf[qg][ks], lacc[qg], 0, 0, 0);
        __builtin_amdgcn_s_setprio(0);

        cur = cur + 1; if (cur == 3) cur = 0;
    }

    // ---- epilogue: O^T/l -> O [B,T,H*64] bf16, 8B packed stores ----
    const int b = bh / N_H, h = bh - b * N_H;
    #pragma unroll
    for (int qg = 0; qg < 2; qg++) {
        const float inv_l = 1.0f / lacc[qg][0];  // all 4 regs hold l(q=lr)
        const int tok = q0 + qg * 16 + lr;
        bf16* Ob = O + ((size_t)b * N_T + tok) * N_D + h * 64;
        #pragma unroll
        for (int dj = 0; dj < 4; dj++) {
            bf16x4 o4;
            #pragma unroll
            for (int r = 0; r < 4; r++) o4[r] = (bf16)(oacc[qg][dj][r] * inv_l);
            *(bf16x4*)(Ob + dj * 16 + lq * 4) = o4;
        }
    }
}

extern "C" void kernel_launch(void* const* d_in, const int* in_sizes, int n_in,
                              void* d_out, int out_size, void* d_ws, size_t ws_size,
                              hipStream_t stream) {
    const float* x      = (const float*)d_in[0];
    const float* W_qkv  = (const float*)d_in[1];
    const float* b_qkv  = (const float*)d_in[2];
    const float* W_proj = (const float*)d_in[3];
    const float* b_proj = (const float*)d_in[4];
    float* out = (float*)d_out;

    char* ws = (char*)d_ws;
    const size_t n_x  = (size_t)M_TOT * N_D;        // 6291456
    const size_t n_wq = (size_t)3 * N_D * N_D;      // 1769472
    const size_t n_wp = (size_t)N_D * N_D;          // 589824
    const size_t sz_qkv = (size_t)N_B * N_H * N_T * N_DH * sizeof(bf16);  // 12.58 MB

    bf16* xb  = (bf16*)(ws);                 ws += n_x * sizeof(bf16);
    bf16* Wqb = (bf16*)(ws);                 ws += n_wq * sizeof(bf16);
    bf16* Wpb = (bf16*)(ws);                 ws += n_wp * sizeof(bf16);
    bf16* Qb  = (bf16*)(ws);                 ws += sz_qkv;
    bf16* Kb  = (bf16*)(ws);                 ws += sz_qkv;
    bf16* Vtb = (bf16*)(ws);                 ws += sz_qkv;
    bf16* Ob  = (bf16*)(ws);

    dim3 blk(256);
    f2bf3<<<dim3((int)((n_x + n_wq + n_wp) / 1024)), blk, 0, stream>>>(
        x, xb, (int)n_x, W_qkv, Wqb, (int)n_wq, W_proj, Wpb);

    gemm_qkv<<<dim3(M_TOT / 128, 2304 / 128), blk, 0, stream>>>(xb, Wqb, b_qkv, Qb, Kb, Vtb);
    attn<<<dim3(768), dim3(256), 0, stream>>>(Qb, Kb, Vtb, Ob);
    gemm_proj<<<dim3(M_TOT / 128, 768 / 64), blk, 0, stream>>>(Ob, Wpb, b_proj, out);
}